// Round 5
// baseline (120.174 us; speedup 1.0000x reference)
//
#include <hip/hip_runtime.h>
#include <hip/hip_bf16.h>

#define N_NODES 100000
#define N_EDGES 1600000
#define K_DIM 128
#define N_DIM 128
#define BM_WORDS 3125        // ceil(100000/32)
#define PART_STRIDE 3136     // per-block partial-mask stride, 64B-multiple
#define FLAG_BLOCKS 256
#define WIMG_WORDS 8192      // 32 KB bf16 W LDS-image at d_ws words [0, 8192)
#define PART_OFF 8192        // word offset of partials in d_ws
#define BROWS 64             // rows per gemm tile
#define GBLOCKS 512          // persistent gemm blocks (2/CU)
#define N_TILES 1563         // ceil(100000/64)
#define TILE_REM 27          // 1563 - 3*512: blocks 0..26 own a 4th tile

typedef __attribute__((ext_vector_type(8))) short bf16x8;   // 8 bf16 = 4 VGPRs
typedef __attribute__((ext_vector_type(4))) float f32x4;    // MFMA accumulator

__device__ inline unsigned short f2bf(float f) {
    __hip_bfloat16 b = __float2bfloat16(f);
    return __builtin_bit_cast(unsigned short, b);
}

// Phase A: per-block private bitmask in LDS (LDS atomics only), written to a
// DISJOINT partial-mask region with plain coalesced stores. Zero global
// atomics. Blocks 0..15 also build the 32 KB bf16 LDS-image of W
// (column-major k-contiguous, XOR-swizzled) for the gemm's global_load_lds.
// Rebuilt every launch -> workspace re-poisoning is harmless.
__global__ __launch_bounds__(256)
void flag_partial(const int* __restrict__ ei, const float* __restrict__ wf,
                  unsigned int* __restrict__ wimg,
                  unsigned int* __restrict__ parts) {
    __shared__ unsigned int lbm[BM_WORDS];

    if (blockIdx.x < 16 && threadIdx.x < 128) {
        int g  = blockIdx.x * 128 + threadIdx.x;   // granule 0..2047
        int n  = g >> 4;                           // W column (output ch)
        int k0 = (g & 15) << 3;                    // k-chunk base
        unsigned short tmp[8];
#pragma unroll
        for (int j = 0; j < 8; ++j) tmp[j] = f2bf(wf[(k0 + j) * N_DIM + n]);
        int byte = (n * 256 + k0 * 2) ^ ((n & 7) << 4);   // swizzled LDS image
        *(uint4*)((char*)wimg + byte) = *(const uint4*)tmp;
    }

    for (int i = threadIdx.x; i < BM_WORDS; i += 256) lbm[i] = 0;
    __syncthreads();

    // int64-as-int32-pairs vs int32 sniff (high words of non-neg int64 are 0)
    bool is64 = ((ei[1] | ei[3] | ei[5] | ei[7]) == 0);
    const int base = blockIdx.x * (N_EDGES / FLAG_BLOCKS);   // 6250 edges/block
    if (is64) {
        const uint4* p = (const uint4*)(ei + 2 * N_EDGES + 2 * base);
        for (int t = threadIdx.x; t < 3125; t += 256) {
            uint4 v = p[t];
            atomicOr(&lbm[v.x >> 5], 1u << (v.x & 31));
            atomicOr(&lbm[v.z >> 5], 1u << (v.z & 31));
        }
    } else {
        const uint2* p = (const uint2*)(ei + N_EDGES + base);  // base even -> 8B-aligned
        for (int t = threadIdx.x; t < 3125; t += 256) {
            uint2 v = p[t];
            atomicOr(&lbm[v.x >> 5], 1u << (v.x & 31));
            atomicOr(&lbm[v.y >> 5], 1u << (v.y & 31));
        }
    }
    __syncthreads();

    unsigned int* dst = parts + (size_t)blockIdx.x * PART_STRIDE;
    for (int i = threadIdx.x; i < BM_WORDS; i += 256) dst[i] = lbm[i];
}

__device__ __forceinline__ void load_a(const float* __restrict__ xf, int tile,
                                       int tid, f32x4 a0[4], f32x4 a1[4]) {
    const int rb0 = tile * BROWS;
#pragma unroll
    for (int i = 0; i < 4; ++i) {
        int c  = i * 256 + tid;           // chunk 0..1023 (16 chunks/row)
        int rl = c >> 4;                  // local row 0..63
        int k8 = c & 15;                  // 8-elem k-chunk
        int rg = rb0 + rl;
        if (rg >= N_NODES) rg = N_NODES - 1;   // clamp: loads stay safe
        a0[i] = *(const f32x4*)(xf + (size_t)rg * K_DIM + k8 * 8);
        a1[i] = *(const f32x4*)(xf + (size_t)rg * K_DIM + k8 * 8 + 4);
    }
}

__device__ __forceinline__ void cvt_write_a(unsigned short* lds, int tid,
                                            const f32x4 a0[4], const f32x4 a1[4]) {
#pragma unroll
    for (int i = 0; i < 4; ++i) {
        int c  = i * 256 + tid;
        int rl = c >> 4;
        int k8 = c & 15;
        unsigned short t8[8];
#pragma unroll
        for (int j = 0; j < 4; ++j) {
            t8[j]     = f2bf(a0[i][j]);
            t8[4 + j] = f2bf(a1[i][j]);
        }
        int byte = (rl * 256 + k8 * 16) ^ ((rl & 7) << 4);
        *(uint4*)((char*)lds + byte) = *(const uint4*)t8;
    }
}

// out[n,:] = hasedge[n] ? (x @ W)[n,:] : 0.  fp32 in, bf16 MFMA, fp32 store.
// PERSISTENT: 512 blocks (2/CU), each owns 3-4 tiles of 64 rows. W staged
// once per block (global_load_lds from precomputed image). A double-buffered
// in LDS with a 2-phase cross-tile pipeline: next tile's global loads + mask
// load issue BEFORE this tile's MFMA phase, so their latency hides under
// compute instead of being serially exposed per block. lmask parity-buffered;
// all cross-iteration LDS hazards separated by the per-tile barrier.
__global__ __launch_bounds__(256, 2)
void gemm_fused(const float* __restrict__ xf,
                const unsigned int* __restrict__ wimg,
                const unsigned int* __restrict__ parts,
                float* __restrict__ out) {
    __shared__ __attribute__((aligned(16))) unsigned short ldsW[N_DIM * 128];    // 32 KB
    __shared__ __attribute__((aligned(16))) unsigned short ldsA[2][BROWS * 128]; // 2x16 KB
    __shared__ unsigned int lmask[2][4][2];  // [tile parity][wave][mask word]

    const int tid  = threadIdx.x;
    const int lane = tid & 63;
    const int wave = tid >> 6;
    const int nt   = 3 + (blockIdx.x < TILE_REM ? 1 : 0);

    // ---- W: staged ONCE per persistent block (identity-mapped, pre-swizzled)
#pragma unroll
    for (int i = 0; i < 8; ++i) {
        int off = i * 4096 + wave * 1024;            // bytes, wave-uniform
        __builtin_amdgcn_global_load_lds(
            (const __attribute__((address_space(1))) unsigned int*)
                ((const char*)wimg + off + lane * 16),
            (__attribute__((address_space(3))) unsigned int*)
                ((char*)ldsW + off),
            16, 0, 0);
    }

    // ---- prologue: tile0 A + mask into flight, stage into buf0
    f32x4 a0[4], a1[4];
    load_a(xf, blockIdx.x, tid, a0, a1);
    uint2 pv = *(const uint2*)(parts + (size_t)tid * PART_STRIDE + blockIdx.x * 2);
    cvt_write_a(ldsA[0], tid, a0, a1);
    __syncthreads();   // drains W global_load_lds + buf0 writes

    const int m    = lane & 15;   // A row / B col / C col
    const int quad = lane >> 4;   // 0..3
    const int arow = wave * 16 + m;
    const int abyt = (arow * 256) ^ ((arow & 7) << 4);

    for (int it = 0; it < nt; ++it) {
        const int cur    = it & 1;
        const int tile   = blockIdx.x + it * GBLOCKS;
        const bool more  = (it + 1 < nt);

        // issue next tile's A loads + mask load (latency hides under MFMA)
        uint2 pvn;
        if (more) {
            load_a(xf, tile + GBLOCKS, tid, a0, a1);
            pvn = *(const uint2*)(parts + (size_t)tid * PART_STRIDE +
                                  (tile + GBLOCKS) * 2);
        }

        // ---- compute on buf[cur]
        f32x4 acc[8];
#pragma unroll
        for (int t = 0; t < 8; ++t) acc[t] = (f32x4){0.f, 0.f, 0.f, 0.f};
#pragma unroll
        for (int kk = 0; kk < 4; ++kk) {
            const int kbase = kk * 32 + quad * 8;
            bf16x8 af = *(const bf16x8*)((const char*)ldsA[cur] +
                                         (abyt ^ (kbase * 2)));
#pragma unroll
            for (int t = 0; t < 8; ++t) {
                int bn = t * 16 + m;
                int bbyte = (bn * 256 + kbase * 2) ^ ((bn & 7) << 4);
                bf16x8 bfrag = *(const bf16x8*)((const char*)ldsW + bbyte);
                acc[t] = __builtin_amdgcn_mfma_f32_16x16x32_bf16(af, bfrag,
                                                                 acc[t], 0, 0, 0);
            }
        }

        // ---- wave-reduce this tile's mask (pv was loaded one tile ahead)
        unsigned int m0 = pv.x, m1 = pv.y;
#pragma unroll
        for (int off = 32; off; off >>= 1) {
            m0 |= __shfl_xor(m0, off);
            m1 |= __shfl_xor(m1, off);
        }
        if (lane == 0) { lmask[cur][wave][0] = m0; lmask[cur][wave][1] = m1; }

        // ---- stage next tile into buf[cur^1]
        if (more) cvt_write_a(ldsA[cur ^ 1], tid, a0, a1);
        __syncthreads();   // buf[nxt] ready; lmask visible; buf[cur] reads done

        // ---- masked epilogue for this tile
        const unsigned int fm0 = lmask[cur][0][0] | lmask[cur][1][0] |
                                 lmask[cur][2][0] | lmask[cur][3][0];
        const unsigned int fm1 = lmask[cur][0][1] | lmask[cur][1][1] |
                                 lmask[cur][2][1] | lmask[cur][3][1];
        const int rb0 = tile * BROWS;
#pragma unroll
        for (int r = 0; r < 4; ++r) {
            int lrow = wave * 16 + quad * 4 + r;   // 0..63
            int orow = rb0 + lrow;
            if (orow < N_NODES) {
                unsigned int w = (lrow & 32) ? fm1 : fm0;
                float fmul = ((w >> (lrow & 31)) & 1) ? 1.0f : 0.0f;
#pragma unroll
                for (int t = 0; t < 8; ++t)
                    out[(size_t)orow * N_DIM + t * 16 + m] = acc[t][r] * fmul;
            }
        }
        pv = pvn;
    }
}

extern "C" void kernel_launch(void* const* d_in, const int* in_sizes, int n_in,
                              void* d_out, int out_size, void* d_ws, size_t ws_size,
                              hipStream_t stream) {
    const float* x = (const float*)d_in[0];
    const float* w = (const float*)d_in[1];
    // d_in[2] (att) is mathematically irrelevant: normalized attention weights
    // sum to s/(s+1e-16) == 1 per segment in fp32, and the reference
    // aggregates h[col]*alpha into col, so out[n] = h[n] (or 0 if no in-edge).
    const int* ei = (const int*)d_in[3];
    float* out = (float*)d_out;

    unsigned int* wimg  = (unsigned int*)d_ws;            // 32 KB W LDS-image
    unsigned int* parts = (unsigned int*)d_ws + PART_OFF; // 256 partial masks

    flag_partial<<<FLAG_BLOCKS, 256, 0, stream>>>(ei, w, wimg, parts);
    gemm_fused<<<GBLOCKS, 256, 0, stream>>>(x, wimg, parts, out);
}